// Round 6
// baseline (277.382 us; speedup 1.0000x reference)
//
#include <hip/hip_runtime.h>

typedef __attribute__((ext_vector_type(8))) short short8;
typedef __attribute__((ext_vector_type(4))) float f32x4;
typedef __attribute__((ext_vector_type(16))) float f32x16;
typedef __attribute__((ext_vector_type(2))) unsigned int u32x2;
typedef __attribute__((ext_vector_type(4))) unsigned int u32x4;
typedef unsigned short u16;
typedef unsigned int u32;

#define MFMA16(a, b, c) __builtin_amdgcn_mfma_f32_16x16x32_bf16((a), (b), (c), 0, 0, 0)
#define MFMA32(a, b, c) __builtin_amdgcn_mfma_f32_32x32x16_bf16((a), (b), (c), 0, 0, 0)

#define BATCH 8
#define NTOK 4096
#define CDIM 256
#define CQK 32
#define LOG2E 1.4426950408889634f

__device__ __forceinline__ u16 f2bf(float f) {
  u32 u = __float_as_uint(f);
  return (u16)((u + 0x7FFFu + ((u >> 16) & 1u)) >> 16);
}
// pack two f32 -> two bf16 (round-half-up) in one u32: bf(a) | bf(b)<<16
__device__ __forceinline__ u32 pack2(float a, float b) {
  const u32 ua = __float_as_uint(a) + 0x8000u;
  const u32 ub = __float_as_uint(b) + 0x8000u;
#if __has_builtin(__builtin_amdgcn_perm)
  return __builtin_amdgcn_perm(ub, ua, 0x07060302u);
#else
  return (ua >> 16) | (ub & 0xFFFF0000u);
#endif
}
__device__ __forceinline__ float fexp2(float x) {
#if __has_builtin(__builtin_amdgcn_exp2f)
  return __builtin_amdgcn_exp2f(x);
#else
  return exp2f(x);
#endif
}

// ---------------------------------------------------------------------------
// Kernel 0: weights -> MFMA B-fragment order + f32 bias.
// ---------------------------------------------------------------------------
__global__ void k_prep(const float* __restrict__ Wq, const float* __restrict__ bq,
                       const float* __restrict__ Wk, const float* __restrict__ bk,
                       const float* __restrict__ Wv, const float* __restrict__ bv,
                       u16* __restrict__ wtf, float* __restrict__ bias) {
  const int f = blockIdx.x;        // 0..159 = ct*8+ks
  const int L = threadIdx.x;       // 0..63
  const int ct = f >> 3, ks = f & 7;
  const int o = ct * 16 + (L & 15);
  const int ch = ks * 32 + (L >> 4) * 8;
  short8 v8;
#pragma unroll
  for (int jj = 0; jj < 8; jj++) {
    const int c = ch + jj;
    float v;
    if (o < 32)       v = Wq[c * CQK + o];
    else if (o < 64)  v = Wk[c * CQK + (o - 32)];
    else              v = Wv[c * CDIM + (o - 64)];
    v8[jj] = (short)f2bf(v);
  }
  *(short8*)(wtf + (size_t)f * 512 + L * 8) = v8;
  if (f == 0) {
    for (int i = L; i < 320; i += 64) {
      if (i < 32)      bias[i] = bq[i];
      else if (i < 64) bias[i] = bk[i - 32];
      else             bias[i] = bv[i - 64];
    }
  }
}

// ---------------------------------------------------------------------------
// Kernel 1: fused cvt+proj. K outputs pre-scaled by log2(e) (exp2 trick).
// V^T stored with n-groups-of-4 bit-swapped within each 16 (j-order
// permutation phi = {0-3, 8-11, 4-7, 12-15}) so k_attn's V A-fragments are
// single b128 loads matching the natural S^T C-layout reg order.
// ---------------------------------------------------------------------------
__global__ __launch_bounds__(256, 2) void k_proj(
    const float* __restrict__ x, const u16* __restrict__ wtf,
    const float* __restrict__ bias,
    u16* __restrict__ q_ws, u16* __restrict__ k_ws, u16* __restrict__ vt_ws) {
  __shared__ u16 x_lds[64 * 264];
  __shared__ u16 vt_t[64 * 72];
  const int m0 = blockIdx.x * 64;
  const int tid = threadIdx.x;
  const int w = tid >> 6, L = tid & 63;
  const int lr = L & 15, q4 = L >> 4;

  // stage + convert x tile via perm-packs
#pragma unroll
  for (int ii = 0; ii < 8; ii++) {
    const int e = (tid + 256 * ii) * 8;
    const int row = e >> 8, col = e & 255;
    const float* src = x + (size_t)(m0 + row) * CDIM + col;
    f32x4 a = *(const f32x4*)src;
    f32x4 b4 = *(const f32x4*)(src + 4);
    u32x4 pk;
    pk[0] = pack2(a[0], a[1]);
    pk[1] = pack2(a[2], a[3]);
    pk[2] = pack2(b4[0], b4[1]);
    pk[3] = pack2(b4[2], b4[3]);
    *(u32x4*)&x_lds[row * 264 + col] = pk;
  }
  __syncthreads();

  const int mrow = w * 16;
  f32x4 acc[20];
#pragma unroll
  for (int ct = 0; ct < 20; ct++) acc[ct] = (f32x4){0.f, 0.f, 0.f, 0.f};

#pragma unroll
  for (int ks = 0; ks < 8; ks++) {
    short8 a = *(const short8*)&x_lds[(mrow + lr) * 264 + ks * 32 + q4 * 8];
#pragma unroll
    for (int ct = 0; ct < 20; ct++) {
      short8 bf = *(const short8*)(wtf + ((size_t)(ct * 8 + ks)) * 512 + L * 8);
      acc[ct] = MFMA16(a, bf, acc[ct]);
    }
  }

  // q/k epilogue (k scaled by log2e)
#pragma unroll
  for (int ct = 0; ct < 4; ct++) {
    const float bb = bias[ct * 16 + lr];
    const int o = ct * 16 + lr;
#pragma unroll
    for (int r = 0; r < 4; r++) {
      const int row = m0 + mrow + q4 * 4 + r;
      float v = acc[ct][r] + bb;
      if (o < 32) q_ws[(size_t)row * CQK + o] = f2bf(v);
      else        k_ws[(size_t)row * CQK + (o - 32)] = f2bf(v * LOG2E);
    }
  }
  // v epilogue: transpose via LDS; n-group (4s) position = bitswap2(q4)
  const int b = m0 >> 12, nloc = m0 & 4095;
#pragma unroll
  for (int cg = 0; cg < 4; cg++) {
    __syncthreads();
#pragma unroll
    for (int t4 = 0; t4 < 4; t4++) {
      const int ct = 4 + cg * 4 + t4;
      const float bb = bias[ct * 16 + lr];
      const int c_l = t4 * 16 + lr;
      const int n_base = mrow + (((q4 & 1) << 1) | (q4 >> 1)) * 4;
      u32x2 pk;
      pk[0] = pack2(acc[ct][0] + bb, acc[ct][1] + bb);
      pk[1] = pack2(acc[ct][2] + bb, acc[ct][3] + bb);
      *(u32x2*)&vt_t[c_l * 72 + n_base] = pk;
    }
    __syncthreads();
#pragma unroll
    for (int i = 0; i < 2; i++) {
      const int gch = tid + 256 * i;
      const int c_l = gch >> 3, jc = gch & 7;
      short8 v = *(const short8*)&vt_t[c_l * 72 + jc * 8];
      *(short8*)(vt_ws + ((size_t)(b * CDIM + cg * 64 + c_l)) * NTOK + nloc + jc * 8) = v;
    }
  }
}

// ---------------------------------------------------------------------------
// Kernel 2: flash attention, NO LDS, NO BARRIERS. Wave = 64 i x 64 c.
// S^T via 32x32x16 (A=Q, B=K, chained over ch): C-layout col = i = lane&31,
// regs = j. exp2 -> pack pairs -> regs ARE the PV B-fragment under the
// per-16 j-permutation phi (V^T stored permuted to match). O^T = V^T . P^T
// accumulated per (i-tile, c-tile); all operands stream from L2.
// ---------------------------------------------------------------------------
__global__ __launch_bounds__(256, 2) void k_attn(
    const float* __restrict__ x, const u16* __restrict__ q_ws,
    const u16* __restrict__ k_ws, const u16* __restrict__ vt_ws,
    const float* __restrict__ gamma, float* __restrict__ out) {
  const int bid = blockIdx.x;       // 512 = 8 b x 64 i-tiles
  const int b = bid & 7;            // batch -> XCD pinned
  const int it = bid >> 3;
  const int i0 = it * 64;
  const int tid = threadIdx.x;
  const int w = tid >> 6, L = tid & 63;
  const int L31 = L & 31, Lhi = L >> 5;
  const int c0 = w * 64;            // wave's 64 channels

  const u16* qb = q_ws + (size_t)b * NTOK * CQK;
  const u16* kb = k_ws + (size_t)b * NTOK * CQK;
  const u16* vb = vt_ws + ((size_t)(b * CDIM + c0)) * NTOK;

  // K B-frags [i-tile][ch-chain]: lane n=i=L31, k=ch = ch2*16 + Lhi*8 + e
  short8 kf[2][2];
#pragma unroll
  for (int it2 = 0; it2 < 2; it2++)
#pragma unroll
    for (int ch2 = 0; ch2 < 2; ch2++)
      kf[it2][ch2] = *(const short8*)(kb +
          (size_t)(i0 + it2 * 32 + L31) * CQK + ch2 * 16 + Lhi * 8);

  f32x16 acc[2][2];
#pragma unroll
  for (int a2 = 0; a2 < 2; a2++)
#pragma unroll
    for (int b2 = 0; b2 < 2; b2++)
#pragma unroll
      for (int e = 0; e < 16; e++) acc[a2][b2][e] = 0.f;
  float lsum[2] = {0.f, 0.f};

  // Q A-frags double-buffered [buf][j-subtile][ch-chain]: lane m=j=L31
  short8 qf[2][2][2];
#pragma unroll
  for (int jt2 = 0; jt2 < 2; jt2++)
#pragma unroll
    for (int ch2 = 0; ch2 < 2; ch2++)
      qf[0][jt2][ch2] = *(const short8*)(qb +
          (size_t)(jt2 * 32 + L31) * CQK + ch2 * 16 + Lhi * 8);

#define ATTN_ITER(JT, CUR)                                                      \
  do {                                                                          \
    const int j0 = (JT) * 64;                                                   \
    /* V A-frags for THIS iter (consumed at bottom: latency covered) */         \
    short8 vf[2][4];                                                            \
    _Pragma("unroll")                                                           \
    for (int ct2 = 0; ct2 < 2; ct2++)                                           \
      _Pragma("unroll")                                                         \
      for (int kt = 0; kt < 4; kt++)                                            \
        vf[ct2][kt] = *(const short8*)(vb +                                     \
            (size_t)(ct2 * 32 + L31) * NTOK + j0 + kt * 16 + Lhi * 8);          \
    /* Q A-frags for NEXT iter (wrap: values unused on last iter) */            \
    {                                                                           \
      const int jn = (j0 + 64) & (NTOK - 1);                                    \
      _Pragma("unroll")                                                         \
      for (int jt2 = 0; jt2 < 2; jt2++)                                         \
        _Pragma("unroll")                                                       \
        for (int ch2 = 0; ch2 < 2; ch2++)                                       \
          qf[(CUR) ^ 1][jt2][ch2] = *(const short8*)(qb +                       \
              (size_t)(jn + jt2 * 32 + L31) * CQK + ch2 * 16 + Lhi * 8);        \
    }                                                                           \
    /* S^T -> exp2 -> packed P B-frags (natural reg order == B-frag) */         \
    short8 pf[2][4];                                                            \
    _Pragma("unroll")                                                           \
    for (int it2 = 0; it2 < 2; it2++) {                                         \
      _Pragma("unroll")                                                         \
      for (int jt2 = 0; jt2 < 2; jt2++) {                                       \
        f32x16 st;                                                              \
        _Pragma("unroll")                                                       \
        for (int e = 0; e < 16; e++) st[e] = 0.f;                               \
        st = MFMA32(qf[CUR][jt2][0], kf[it2][0], st);                           \
        st = MFMA32(qf[CUR][jt2][1], kf[it2][1], st);                           \
        float p[16];                                                            \
        float ls = 0.f;                                                         \
        _Pragma("unroll")                                                       \
        for (int r = 0; r < 16; r++) {                                          \
          p[r] = fexp2(st[r]);                                                  \
          ls += p[r];                                                           \
        }                                                                       \
        lsum[it2] += ls;                                                        \
        u32x4 lo, hi;                                                           \
        _Pragma("unroll")                                                       \
        for (int q2 = 0; q2 < 4; q2++) {                                        \
          lo[q2] = pack2(p[2 * q2], p[2 * q2 + 1]);                             \
          hi[q2] = pack2(p[8 + 2 * q2], p[9 + 2 * q2]);                         \
        }                                                                       \
        pf[it2][jt2 * 2 + 0] = __builtin_bit_cast(short8, lo);                  \
        pf[it2][jt2 * 2 + 1] = __builtin_bit_cast(short8, hi);                  \
      }                                                                         \
    }                                                                           \
    /* O^T += V^T . P^T */                                                      \
    _Pragma("unroll")                                                           \
    for (int it2 = 0; it2 < 2; it2++)                                           \
      _Pragma("unroll")                                                         \
      for (int ct2 = 0; ct2 < 2; ct2++)                                         \
        _Pragma("unroll")                                                       \
        for (int kt = 0; kt < 4; kt++)                                          \
          acc[it2][ct2] = MFMA32(vf[ct2][kt], pf[it2][kt], acc[it2][ct2]);      \
  } while (0)

  for (int jt2x = 0; jt2x < 64; jt2x += 2) {
    ATTN_ITER(jt2x, 0);
    ATTN_ITER(jt2x + 1, 1);
  }
#undef ATTN_ITER

  // denominators: lane = i for both halves; halves hold disjoint j sets
  const float g = gamma[0];
  float mul[2];
#pragma unroll
  for (int it2 = 0; it2 < 2; it2++) {
    float s2 = lsum[it2] + __shfl_xor(lsum[it2], 32);
    mul[it2] = g / s2;
  }

  // epilogue: out = (O/l)*g + x. C-layout: col=i=L31, row(c) regs 4q..4q+3
  // are consecutive c = 8q + 4*Lhi + 0..3 -> f32x4 loads/stores.
#pragma unroll
  for (int it2 = 0; it2 < 2; it2++) {
    const int row = i0 + it2 * 32 + L31;
#pragma unroll
    for (int ct2 = 0; ct2 < 2; ct2++) {
#pragma unroll
      for (int q2 = 0; q2 < 4; q2++) {
        const int c = c0 + ct2 * 32 + 8 * q2 + 4 * Lhi;
        const size_t idx = ((size_t)(b * NTOK + row)) * CDIM + c;
        f32x4 x4 = *(const f32x4*)(x + idx);
        f32x4 o4;
#pragma unroll
        for (int e = 0; e < 4; e++)
          o4[e] = acc[it2][ct2][4 * q2 + e] * mul[it2] + x4[e];
        *(f32x4*)(out + idx) = o4;
      }
    }
  }
}

// ---------------------------------------------------------------------------
extern "C" void kernel_launch(void* const* d_in, const int* in_sizes, int n_in,
                              void* d_out, int out_size, void* d_ws, size_t ws_size,
                              hipStream_t stream) {
  const float* x  = (const float*)d_in[0];
  const float* Wq = (const float*)d_in[1];
  const float* bq = (const float*)d_in[2];
  const float* Wk = (const float*)d_in[3];
  const float* bk = (const float*)d_in[4];
  const float* Wv = (const float*)d_in[5];
  const float* bv = (const float*)d_in[6];
  const float* gamma = (const float*)d_in[7];
  float* out = (float*)d_out;

  char* ws = (char*)d_ws;
  u16* q_ws  = (u16*)(ws);
  u16* k_ws  = (u16*)(ws + (2u << 20));
  u16* vt_ws = (u16*)(ws + (4u << 20));
  u16* wtf   = (u16*)(ws + (20u << 20));
  float* bias = (float*)(ws + (20u << 20) + (256u << 10));

  k_prep<<<160, 64, 0, stream>>>(Wq, bq, Wk, bk, Wv, bv, wtf, bias);
  k_proj<<<512, 256, 0, stream>>>(x, wtf, bias, q_ws, k_ws, vt_ws);
  k_attn<<<512, 256, 0, stream>>>(x, q_ws, k_ws, vt_ws, gamma, out);
}

// Round 7
// 260.448 us; speedup vs baseline: 1.0650x; 1.0650x over previous
//
#include <hip/hip_runtime.h>

typedef __attribute__((ext_vector_type(8))) short short8;
typedef __attribute__((ext_vector_type(4))) float f32x4;
typedef __attribute__((ext_vector_type(16))) float f32x16;
typedef __attribute__((ext_vector_type(2))) unsigned int u32x2;
typedef __attribute__((ext_vector_type(4))) unsigned int u32x4;
typedef unsigned short u16;
typedef unsigned int u32;

#define MFMA16(a, b, c) __builtin_amdgcn_mfma_f32_16x16x32_bf16((a), (b), (c), 0, 0, 0)
#define MFMA32(a, b, c) __builtin_amdgcn_mfma_f32_32x32x16_bf16((a), (b), (c), 0, 0, 0)

#define BATCH 8
#define NTOK 4096
#define CDIM 256
#define CQK 32
#define LOG2E 1.4426950408889634f
// per-batch q/k pack size == per-(batch,cblk) v pack size = 131072 u16 = 256KB
#define QK_B 131072

__device__ __forceinline__ u16 f2bf(float f) {
  u32 u = __float_as_uint(f);
  return (u16)((u + 0x7FFFu + ((u >> 16) & 1u)) >> 16);
}
__device__ __forceinline__ u32 pack2(float a, float b) {
  const u32 ua = __float_as_uint(a) + 0x8000u;
  const u32 ub = __float_as_uint(b) + 0x8000u;
#if __has_builtin(__builtin_amdgcn_perm)
  return __builtin_amdgcn_perm(ub, ua, 0x07060302u);
#else
  return (ua >> 16) | (ub & 0xFFFF0000u);
#endif
}
__device__ __forceinline__ float fexp2(float x) {
#if __has_builtin(__builtin_amdgcn_exp2f)
  return __builtin_amdgcn_exp2f(x);
#else
  return exp2f(x);
#endif
}

// ---------------------------------------------------------------------------
// Kernel 0: weights -> MFMA B-fragment order + f32 bias (unchanged).
// ---------------------------------------------------------------------------
__global__ void k_prep(const float* __restrict__ Wq, const float* __restrict__ bq,
                       const float* __restrict__ Wk, const float* __restrict__ bk,
                       const float* __restrict__ Wv, const float* __restrict__ bv,
                       u16* __restrict__ wtf, float* __restrict__ bias) {
  const int f = blockIdx.x;        // 0..159 = ct*8+ks
  const int L = threadIdx.x;       // 0..63
  const int ct = f >> 3, ks = f & 7;
  const int o = ct * 16 + (L & 15);
  const int ch = ks * 32 + (L >> 4) * 8;
  short8 v8;
#pragma unroll
  for (int jj = 0; jj < 8; jj++) {
    const int c = ch + jj;
    float v;
    if (o < 32)       v = Wq[c * CQK + o];
    else if (o < 64)  v = Wk[c * CQK + (o - 32)];
    else              v = Wv[c * CDIM + (o - 64)];
    v8[jj] = (short)f2bf(v);
  }
  *(short8*)(wtf + (size_t)f * 512 + L * 8) = v8;
  if (f == 0) {
    for (int i = L; i < 320; i += 64) {
      if (i < 32)      bias[i] = bq[i];
      else if (i < 64) bias[i] = bk[i - 32];
      else             bias[i] = bv[i - 64];
    }
  }
}

// ---------------------------------------------------------------------------
// Kernel 1: fused cvt+proj. Outputs packed in MFMA-FRAGMENT order so k_attn's
// loads are lane-contiguous 1KB chunks:
//  q_pack/k_pack[b]: chunk(jblk = j>>5, ch2) elem[L*8+e] =
//      M[jblk*32 + (L&31)][ch2*16 + (L>>5)*8 + e]    (k pre-scaled by log2e)
//  v_pack[(b,cblk=c>>5)]: chunk(jt = j>>6, kt) elem[L*8+e] =
//      V^T[cblk*32 + (L&31)][jt*64 + phi(kt, L>>5, e)]
//  phi(kt,Lhi,e) = (kt>>1)*32 + (kt&1)*16 + 4*Lhi + (e&3) + 8*(e>>2)
//  (phi = the 32x32 MFMA C-layout row order -> PV B-frag k-slot map, HW-
//   validated by R6's passing bitswap variant).
// ---------------------------------------------------------------------------
__global__ __launch_bounds__(256, 2) void k_proj(
    const float* __restrict__ x, const u16* __restrict__ wtf,
    const float* __restrict__ bias,
    u16* __restrict__ q_pack, u16* __restrict__ k_pack, u16* __restrict__ v_pack) {
  __shared__ u16 x_lds[64 * 264];
  __shared__ u16 vt_t[64 * 76];    // stride 76: conflict-free write & read phases
  const int m0 = blockIdx.x * 64;
  const int tid = threadIdx.x;
  const int w = tid >> 6, L = tid & 63;
  const int lr = L & 15, q4 = L >> 4;

  // stage + convert x tile via perm-packs
#pragma unroll
  for (int ii = 0; ii < 8; ii++) {
    const int e = (tid + 256 * ii) * 8;
    const int row = e >> 8, col = e & 255;
    const float* src = x + (size_t)(m0 + row) * CDIM + col;
    f32x4 a = *(const f32x4*)src;
    f32x4 b4 = *(const f32x4*)(src + 4);
    u32x4 pk;
    pk[0] = pack2(a[0], a[1]);
    pk[1] = pack2(a[2], a[3]);
    pk[2] = pack2(b4[0], b4[1]);
    pk[3] = pack2(b4[2], b4[3]);
    *(u32x4*)&x_lds[row * 264 + col] = pk;
  }
  __syncthreads();

  const int mrow = w * 16;
  f32x4 acc[20];
#pragma unroll
  for (int ct = 0; ct < 20; ct++) acc[ct] = (f32x4){0.f, 0.f, 0.f, 0.f};

#pragma unroll
  for (int ks = 0; ks < 8; ks++) {
    short8 a = *(const short8*)&x_lds[(mrow + lr) * 264 + ks * 32 + q4 * 8];
#pragma unroll
    for (int ct = 0; ct < 20; ct++) {
      short8 bf = *(const short8*)(wtf + ((size_t)(ct * 8 + ks)) * 512 + L * 8);
      acc[ct] = MFMA16(a, bf, acc[ct]);
    }
  }

  const int b = m0 >> 12, nloc = m0 & 4095, jt = nloc >> 6;

  // q/k epilogue -> fragment-order packs (scalar scatter, as before)
#pragma unroll
  for (int ct = 0; ct < 4; ct++) {
    const float bb = bias[ct * 16 + lr];
    const int o = ct * 16 + lr;
    const int ch = o & 31;
    const int ch2 = ch >> 4, chb = (ch >> 3) & 1, e = ch & 7;
    u16* dst = (o < 32 ? q_pack : k_pack) + (size_t)b * QK_B;
    const float sc = (o < 32) ? 1.0f : LOG2E;
#pragma unroll
    for (int r = 0; r < 4; r++) {
      const int j = nloc + mrow + q4 * 4 + r;
      const size_t elem = ((size_t)(j >> 5) * 2 + ch2) * 512 +
                          (size_t)((chb << 5) + (j & 31)) * 8 + e;
      dst[elem] = f2bf((acc[ct][r] + bb) * sc);
    }
  }

  // v epilogue: transpose via LDS (natural n order), then phi-packed stores
#pragma unroll
  for (int cg = 0; cg < 4; cg++) {
    __syncthreads();
#pragma unroll
    for (int t4 = 0; t4 < 4; t4++) {
      const int ct = 4 + cg * 4 + t4;
      const float bb = bias[ct * 16 + lr];
      const int c_l = t4 * 16 + lr;
      const int n_base = mrow + q4 * 4;
      u32x2 pk;
      pk[0] = pack2(acc[ct][0] + bb, acc[ct][1] + bb);
      pk[1] = pack2(acc[ct][2] + bb, acc[ct][3] + bb);
      *(u32x2*)&vt_t[c_l * 76 + n_base] = pk;
    }
    __syncthreads();
    // 512 chunks: gch = cblk_l*256 + kt*64 + Lg; each chunk = 16B of v_pack
#pragma unroll
    for (int i = 0; i < 2; i++) {
      const int gch = tid + 256 * i;
      const int cblk_l = gch >> 8, kt = (gch >> 6) & 3, Lg = gch & 63;
      const int Lhi = Lg >> 5, L31 = Lg & 31;
      const int c_l = cblk_l * 32 + L31;
      const int n0 = (kt >> 1) * 32 + (kt & 1) * 16 + 4 * Lhi;
      u32x2 a = *(const u32x2*)&vt_t[c_l * 76 + n0];      // j n0..n0+3
      u32x2 bq2 = *(const u32x2*)&vt_t[c_l * 76 + n0 + 8]; // j n0+8..n0+11
      u32x4 outv = (u32x4){a[0], a[1], bq2[0], bq2[1]};
      const size_t off = (size_t)(b * 8 + cg * 2 + cblk_l) * QK_B +
                         (size_t)jt * 2048 + (size_t)kt * 512 + (size_t)Lg * 8;
      *(u32x4*)(v_pack + off) = outv;
    }
  }
}

// ---------------------------------------------------------------------------
// Kernel 2: flash attention, NO LDS/barriers; ALL loads lane-contiguous 1KB
// fragment chunks. Wave = 64 i x 64 c. Q and V register-double-buffered one
// j-tile ahead. S^T 32x32x16 C-layout regs are directly the PV B-fragment
// (phi baked into v_pack). O^T accumulated; single shfl for denominators.
// ---------------------------------------------------------------------------
__global__ __launch_bounds__(256, 2) void k_attn(
    const float* __restrict__ x, const u16* __restrict__ qp,
    const u16* __restrict__ kp, const u16* __restrict__ vp,
    const float* __restrict__ gamma, float* __restrict__ out) {
  const int bid = blockIdx.x;       // 512 = 8 b x 64 i-tiles
  const int b = bid & 7;            // batch -> XCD pinned
  const int it = bid >> 3;
  const int tid = threadIdx.x;
  const int w = tid >> 6, L = tid & 63;
  const int L31 = L & 31, Lhi = L >> 5;
  const int c0 = w * 64;
  const int i0 = it * 64;

  const u16* qb = qp + (size_t)b * QK_B + (size_t)L * 8;
  const u16* kb = kp + (size_t)b * QK_B + (size_t)L * 8;
  const u16* vb = vp + (size_t)(b * 8 + w * 2) * QK_B + (size_t)L * 8;

  // K B-frags, resident all kernel: chunk(iblk = it*2+it2, ch2)
  short8 kf[2][2];
#pragma unroll
  for (int it2 = 0; it2 < 2; it2++)
#pragma unroll
    for (int ch2 = 0; ch2 < 2; ch2++)
      kf[it2][ch2] = *(const short8*)(kb + ((size_t)((it * 2 + it2) * 2 + ch2)) * 512);

  f32x16 acc[2][2];
#pragma unroll
  for (int a2 = 0; a2 < 2; a2++)
#pragma unroll
    for (int b2 = 0; b2 < 2; b2++)
#pragma unroll
      for (int e = 0; e < 16; e++) acc[a2][b2][e] = 0.f;
  float lsum[2] = {0.f, 0.f};

  // double-buffered Q A-frags and V A-frags
  short8 qf[2][2][2];
  short8 vf[2][2][4];
#pragma unroll
  for (int jt2 = 0; jt2 < 2; jt2++)
#pragma unroll
    for (int ch2 = 0; ch2 < 2; ch2++)
      qf[0][jt2][ch2] = *(const short8*)(qb + ((size_t)(jt2 * 2 + ch2)) * 512);
#pragma unroll
  for (int ct2 = 0; ct2 < 2; ct2++)
#pragma unroll
    for (int kt = 0; kt < 4; kt++)
      vf[0][ct2][kt] = *(const short8*)(vb + (size_t)ct2 * QK_B + (size_t)kt * 512);

#define ATTN_ITER(JT, CUR)                                                      \
  do {                                                                          \
    const int jtn = ((JT) + 1) & 63;                                            \
    /* prefetch next V (full iter of slack before use) */                       \
    _Pragma("unroll")                                                           \
    for (int ct2 = 0; ct2 < 2; ct2++)                                           \
      _Pragma("unroll")                                                         \
      for (int kt = 0; kt < 4; kt++)                                            \
        vf[(CUR) ^ 1][ct2][kt] = *(const short8*)(vb + (size_t)ct2 * QK_B +     \
            (size_t)(jtn * 4 + kt) * 512);                                      \
    /* prefetch next Q */                                                       \
    _Pragma("unroll")                                                           \
    for (int jt2 = 0; jt2 < 2; jt2++)                                           \
      _Pragma("unroll")                                                         \
      for (int ch2 = 0; ch2 < 2; ch2++)                                         \
        qf[(CUR) ^ 1][jt2][ch2] = *(const short8*)(qb +                         \
            (size_t)(jtn * 4 + jt2 * 2 + ch2) * 512);                           \
    /* per i-subtile: S^T -> exp2 -> packed P B-frag -> PV */                   \
    _Pragma("unroll")                                                           \
    for (int it2 = 0; it2 < 2; it2++) {                                         \
      short8 pf[4];                                                             \
      _Pragma("unroll")                                                         \
      for (int jt2 = 0; jt2 < 2; jt2++) {                                       \
        f32x16 st;                                                              \
        _Pragma("unroll")                                                       \
        for (int e = 0; e < 16; e++) st[e] = 0.f;                               \
        st = MFMA32(qf[CUR][jt2][0], kf[it2][0], st);                           \
        st = MFMA32(qf[CUR][jt2][1], kf[it2][1], st);                           \
        float p[16];                                                            \
        float ls = 0.f;                                                         \
        _Pragma("unroll")                                                       \
        for (int r = 0; r < 16; r++) {                                          \
          p[r] = fexp2(st[r]);                                                  \
          ls += p[r];                                                           \
        }                                                                       \
        lsum[it2] += ls;                                                        \
        u32x4 lo, hi;                                                           \
        _Pragma("unroll")                                                       \
        for (int q2 = 0; q2 < 4; q2++) {                                        \
          lo[q2] = pack2(p[2 * q2], p[2 * q2 + 1]);                             \
          hi[q2] = pack2(p[8 + 2 * q2], p[9 + 2 * q2]);                         \
        }                                                                       \
        pf[jt2 * 2 + 0] = __builtin_bit_cast(short8, lo);                       \
        pf[jt2 * 2 + 1] = __builtin_bit_cast(short8, hi);                       \
      }                                                                         \
      _Pragma("unroll")                                                         \
      for (int ct2 = 0; ct2 < 2; ct2++)                                         \
        _Pragma("unroll")                                                       \
        for (int kt = 0; kt < 4; kt++)                                          \
          acc[it2][ct2] = MFMA32(vf[CUR][ct2][kt], pf[kt], acc[it2][ct2]);      \
    }                                                                           \
  } while (0)

  for (int jt2x = 0; jt2x < 64; jt2x += 2) {
    ATTN_ITER(jt2x, 0);
    ATTN_ITER(jt2x + 1, 1);
  }
#undef ATTN_ITER

  // denominators: lane = i for both Lhi halves (disjoint j sets)
  const float g = gamma[0];
  float mul[2];
#pragma unroll
  for (int it2 = 0; it2 < 2; it2++) {
    float s2 = lsum[it2] + __shfl_xor(lsum[it2], 32);
    mul[it2] = g / s2;
  }

  // epilogue: out = (O/l)*g + x. C-layout: col=i=L31; regs 4q..4q+3 are
  // consecutive c = ct2*32 + 8q + 4*Lhi -> f32x4 I/O.
#pragma unroll
  for (int it2 = 0; it2 < 2; it2++) {
    const int row = i0 + it2 * 32 + L31;
#pragma unroll
    for (int ct2 = 0; ct2 < 2; ct2++) {
#pragma unroll
      for (int q2 = 0; q2 < 4; q2++) {
        const int c = c0 + ct2 * 32 + 8 * q2 + 4 * Lhi;
        const size_t idx = ((size_t)(b * NTOK + row)) * CDIM + c;
        f32x4 x4 = *(const f32x4*)(x + idx);
        f32x4 o4;
#pragma unroll
        for (int e = 0; e < 4; e++)
          o4[e] = acc[it2][ct2][4 * q2 + e] * mul[it2] + x4[e];
        *(f32x4*)(out + idx) = o4;
      }
    }
  }
}

// ---------------------------------------------------------------------------
extern "C" void kernel_launch(void* const* d_in, const int* in_sizes, int n_in,
                              void* d_out, int out_size, void* d_ws, size_t ws_size,
                              hipStream_t stream) {
  const float* x  = (const float*)d_in[0];
  const float* Wq = (const float*)d_in[1];
  const float* bq = (const float*)d_in[2];
  const float* Wk = (const float*)d_in[3];
  const float* bk = (const float*)d_in[4];
  const float* Wv = (const float*)d_in[5];
  const float* bv = (const float*)d_in[6];
  const float* gamma = (const float*)d_in[7];
  float* out = (float*)d_out;

  char* ws = (char*)d_ws;
  u16* q_pack = (u16*)(ws);
  u16* k_pack = (u16*)(ws + (2u << 20));
  u16* v_pack = (u16*)(ws + (4u << 20));
  u16* wtf    = (u16*)(ws + (20u << 20));
  float* bias = (float*)(ws + (20u << 20) + (256u << 10));

  k_prep<<<160, 64, 0, stream>>>(Wq, bq, Wk, bk, Wv, bv, wtf, bias);
  k_proj<<<512, 256, 0, stream>>>(x, wtf, bias, q_pack, k_pack, v_pack);
  k_attn<<<512, 256, 0, stream>>>(x, q_pack, k_pack, v_pack, gamma, out);
}